// Round 16
// baseline (613.200 us; speedup 1.0000x reference)
//
#include <hip/hip_runtime.h>
#include <math.h>

#define NB 16
#define WD 128

typedef __bf16 bf16_t;
typedef __bf16 bf16x8 __attribute__((ext_vector_type(8)));
typedef __bf16 bf16x4 __attribute__((ext_vector_type(4)));
typedef float f32x4 __attribute__((ext_vector_type(4)));

// DPP row_shr inclusive-scan sum within each 16-lane group. row_shr:N moves
// lane i-N's value TO lane i, so the scan accumulates toward HIGHER lanes:
// lane ln==15 holds the full 16-lane group sum. Pure VALU (no LDS pipe).
__device__ inline float rowsum16(float v) {
  int t;
  t = __builtin_amdgcn_update_dpp(0, __float_as_int(v), 0x111, 0xf, 0xf, true);
  v += __int_as_float(t);
  t = __builtin_amdgcn_update_dpp(0, __float_as_int(v), 0x112, 0xf, 0xf, true);
  v += __int_as_float(t);
  t = __builtin_amdgcn_update_dpp(0, __float_as_int(v), 0x114, 0xf, 0xf, true);
  v += __int_as_float(t);
  t = __builtin_amdgcn_update_dpp(0, __float_as_int(v), 0x118, 0xf, 0xf, true);
  v += __int_as_float(t);
  return v;
}

// Full 64-lane sum via DPP: rowsum16, then row_bcast15 (0x142), then
// row_bcast31 (0x143). Lane 63 ends with the full wave sum. (verified r25/r29)
__device__ inline float sum64(float v) {
  v = rowsum16(v);
  int t = __builtin_amdgcn_update_dpp(0, __float_as_int(v), 0x142, 0xf, 0xf, true);
  v += __int_as_float(t);
  t = __builtin_amdgcn_update_dpp(0, __float_as_int(v), 0x143, 0xf, 0xf, true);
  v += __int_as_float(t);
  return v;
}

// ---------------- zero helper ----------------
__global__ void zero_k(float* __restrict__ p, int n) {
  int i = blockIdx.x * 256 + threadIdx.x;
  if (i < n) p[i] = 0.f;
}

// ---------------- combined border zeroing for xmT buffers ----------------
__global__ void zb_k(bf16_t* __restrict__ out, int Hp, int NCB) {
  int trow = NB * 2 * NCB * 576;
  int tcol = NB * Hp * NCB * 8;
  int i = blockIdx.x * 256 + threadIdx.x;
  bf16x8 z = (bf16x8)(bf16_t)0.f;
  if (i < trow) {
    int e = i % 576;
    int t = i / 576;
    int cb = t % NCB;
    t /= NCB;
    int rsel = t & 1;
    int n = t >> 1;
    int row = rsel ? (Hp + 1) : 0;
    *(bf16x8*)&out[(((size_t)n * (Hp + 2) + row) * NCB + cb) * 4608 + e * 8] = z;
  } else if (i < trow + tcol) {
    int k = i - trow;
    int j = k & 7;
    int t = k >> 3;
    int cb = t % NCB;
    t /= NCB;
    int row = (t % Hp) + 1;
    int n = t / Hp;
    size_t base = (((size_t)n * (Hp + 2) + row) * NCB + cb) * 4608;
    size_t off = (j < 4) ? (size_t)(j * 128) : (size_t)(4096 + (j - 4) * 128 + 8);
    *(bf16x8*)&out[base + off] = z;
  }
}

// ---------------- stage-1 pooled-mask: mnext pool from x ch1 directly ----------------
// r31: replaces maskscale2 for stage 1. Reads x channel-1 (clip inline), OOB
// contributes 1.0 (reference pads mask with constant_values=1.0). Writes ONLY
// the pooled next-mask; scale/mnext are computed inline in pconv1p now.
__global__ void ms1_k(const float* __restrict__ x, float* __restrict__ mpool) {
  const int H = 256, Hp = 128;
  int i = blockIdx.x * 256 + threadIdx.x;
  int tot = NB * Hp * WD;
  if (i >= tot) return;
  int xc = i % WD;
  int t = i / WD;
  int yo = t % Hp;
  int n = t / Hp;
  const float* mch = x + ((size_t)(n * 2 + 1)) * H * WD;
  // row-triple sums for the 4 input rows 2yo-1 .. 2yo+2
  float rs[4];
#pragma unroll
  for (int r4 = 0; r4 < 4; ++r4) {
    int yv = 2 * yo - 1 + r4;
    float s = 0.f;
#pragma unroll
    for (int dx = 0; dx < 3; ++dx) {
      int xv = xc - 1 + dx;
      float v = 1.0f;
      if (yv >= 0 && yv < H && xv >= 0 && xv < WD)
        v = fminf(fmaxf(mch[yv * WD + xv], 0.f), 1.f);
      s += v;
    }
    rs[r4] = s;
  }
  float m0 = rs[0] + rs[1] + rs[2];
  float m1 = rs[1] + rs[2] + rs[3];
  float mx0 = (m0 <= 0.f) ? 0.f : 1.f;
  float mx1 = (m1 <= 0.f) ? 0.f : 1.f;
  mpool[((size_t)n * Hp + yo) * WD + xc] = fmaxf(mx0, mx1);
}

// ---------------- fused mask 3x3 sum -> scale/mnext (2 rows) + (2,1) pool ----------------
// (stages 2-4; reads the pooled mask buffers)
__global__ void maskscale2_k(const float* __restrict__ m, float* __restrict__ scale,
                             float* __restrict__ mnext, float* __restrict__ mpool,
                             int H, float Ci) {
  int Hp = H / 2;
  int i = blockIdx.x * 256 + threadIdx.x;
  int tot = NB * Hp * WD;
  if (i >= tot) return;
  int x = i % WD;
  int t = i / WD;
  int yo = t % Hp;
  int n = t / Hp;
  const float* mn_ = m + (size_t)n * H * WD;
  float mx[2];
#pragma unroll
  for (int r = 0; r < 2; ++r) {
    int y = 2 * yo + r;
    float s = 0.f;
#pragma unroll
    for (int dy = -1; dy <= 1; dy++) {
      int yy = y + dy;
#pragma unroll
      for (int dx = -1; dx <= 1; dx++) {
        int xx = x + dx;
        float v = 1.0f;
        if (yy >= 0 && yy < H && xx >= 0 && xx < WD) v = mn_[yy * WD + xx];
        s += v;
      }
    }
    float valid = Ci * s;
    int p = (n * H + y) * WD + x;
    scale[p] = (9.0f * Ci) / fmaxf(valid, 1.0f);
    float mnx = (valid <= 0.0f) ? 0.f : 1.f;
    mnext[p] = mnx;
    mx[r] = mnx;
  }
  mpool[((size_t)n * Hp + yo) * WD + x] = fmaxf(mx[0], mx[1]);
}

#define PROWS 2048   // partial-row stride for conv stages
#define P1STR 4096   // partial-row stride for stage 1 (1024 blocks x 4 waves)
#define PCO 640      // max Co (q-section offset = PCO*PROWS)

// ---------------- stage-1 direct conv (Ci=1) from x, FUSED scale/mnext +
// POOL + STATS. r31: reads x directly (split_k removed) and computes
// scale/mnext inline from the already-loaded mask patch (OOB=1 rule matches
// reference's constant_values=1.0 pad) -- kills 32MB scale/mnext W+R and the
// 17MB split. Pool + DPP stats as r29 (verified).
__global__ void pconv1p_k(const float* __restrict__ x,
                          const float* __restrict__ w, const float* __restrict__ b,
                          bf16_t* __restrict__ yp, float* __restrict__ part) {
  __shared__ float ws[720];
  __shared__ float bs[80];
  for (int i = threadIdx.x; i < 720; i += 256) ws[i] = w[i];
  if (threadIdx.x < 80) bs[threadIdx.x] = b[threadIdx.x];
  __syncthreads();
  const int H = 256, Hp = 128;
  int p2 = blockIdx.x * 256 + threadIdx.x;  // pooled pixel
  int xc = p2 % WD;
  int t = p2 / WD;
  int yo = t % Hp;
  int n = t / Hp;
  const float* dn = x + ((size_t)(n * 2)) * H * WD;
  const float* mn = x + ((size_t)(n * 2 + 1)) * H * WD;
  float vin[4][3];  // data*mask (OOB = 0, reference pads xm with 0)
  float rs[4];      // mask row-triple sums (OOB = 1)
#pragma unroll
  for (int r4 = 0; r4 < 4; ++r4) {
    int yv = 2 * yo - 1 + r4;
    float s = 0.f;
#pragma unroll
    for (int dx = 0; dx < 3; ++dx) {
      int xv = xc - 1 + dx;
      float u = 0.f, m = 1.0f;
      if (yv >= 0 && yv < H && xv >= 0 && xv < WD) {
        m = fminf(fmaxf(mn[yv * WD + xv], 0.f), 1.f);
        u = dn[yv * WD + xv] * m;
      }
      vin[r4][dx] = u;
      s += m;
    }
    rs[r4] = s;
  }
  float msum0 = rs[0] + rs[1] + rs[2];
  float msum1 = rs[1] + rs[2] + rs[3];
  float sc0 = 9.0f / fmaxf(msum0, 1.0f);
  float sc1 = 9.0f / fmaxf(msum1, 1.0f);
  float mx0 = (msum0 <= 0.f) ? 0.f : 1.f;
  float mx1 = (msum1 <= 0.f) ? 0.f : 1.f;
  bf16_t* outp = yp + ((size_t)(n * Hp + yo) * WD + xc) * 80;
  const int wave = threadIdx.x >> 6;
  const int lane = threadIdx.x & 63;
  const int row = blockIdx.x * 4 + wave;  // partial slot, < P1STR
#pragma unroll
  for (int c8 = 0; c8 < 10; ++c8) {
    bf16x8 o;
    float sA[8], qA[8];
#pragma unroll
    for (int j = 0; j < 8; ++j) {
      int co = c8 * 8 + j;
      float s0 = 0.f, s1 = 0.f;
#pragma unroll
      for (int dy = 0; dy < 3; ++dy)
#pragma unroll
        for (int dx = 0; dx < 3; ++dx) {
          float wv = ws[co * 9 + dy * 3 + dx];
          s0 += wv * vin[dy][dx];
          s1 += wv * vin[dy + 1][dx];
        }
      bf16_t o0 = (bf16_t)((s0 * sc0 + bs[co]) * mx0);
      bf16_t o1 = (bf16_t)((s1 * sc1 + bs[co]) * mx1);
      float f0 = (float)o0, f1 = (float)o1;
      sA[j] = f0 + f1;
      qA[j] = f0 * f0 + f1 * f1;
      o[j] = (bf16_t)fmaxf(f0, f1);  // pre-BN pooled max (BN a>0 commutes)
    }
    *(bf16x8*)(outp + c8 * 8) = o;
#pragma unroll
    for (int j = 0; j < 8; ++j) {
      sA[j] = sum64(sA[j]);
      qA[j] = sum64(qA[j]);
    }
    if (lane == 63) {
#pragma unroll
      for (int j = 0; j < 8; ++j) {
        int co = c8 * 8 + j;
        part[(size_t)co * P1STR + row] = sA[j];
        part[(size_t)PCO * PROWS + (size_t)co * P1STR + row] = qA[j];
      }
    }
  }
}

// ---------------- weight transform: w[co][ci][3][3] fp32 -> wt2 bf16 ----------------
// wt2 index: (((tap*NCB + cb)*4 + g)*Co + co)*8 + j   (ci = cb*32 + g*8 + j)
__global__ void wtrans_k(const float* __restrict__ w, bf16_t* __restrict__ wt2,
                         int Ci, int Co, int NCB, int Co_pad) {
  int idx = blockIdx.x * 256 + threadIdx.x;
  int total = 9 * NCB * Co_pad * 32;
  if (idx >= total) return;
  int j = idx & 7;
  int rest = idx >> 3;
  int co = rest % Co_pad;
  int rest2 = rest / Co_pad;
  int g = rest2 & 3;
  int rest3 = rest2 >> 2;
  int cb = rest3 % NCB;
  int tap = rest3 / NCB;
  int ci = cb * 32 + g * 8 + j;
  float v = 0.f;
  if (co < Co && ci < Ci) v = w[((size_t)co * Ci + ci) * 9 + tap];
  wt2[idx] = (bf16_t)v;
}

// ---------------- MFMA implicit-GEMM 3x3 conv (stages 2-4) ----------------
// r30 core, UNCHANGED (three consecutive model-confirmed results; s4 at its
// A-L1 bound: MfmaUtil 61.5 vs 62.1 modeled; A-reuse invariant nf*rows<=8
// at 160 acc regs closes further gains). Row-outer B sharing (48 reads/wave/
// cb), in-register pre-BN (2,1) pool, fused no-atomic DPP BN stats.
template <int MF>
__global__ __launch_bounds__(256, 2) void convmfma_t(
    const bf16_t* __restrict__ xmT, const bf16_t* __restrict__ wt2,
    const float* __restrict__ bias, const float* __restrict__ scale,
    const float* __restrict__ mnext, bf16_t* __restrict__ y,
    float* __restrict__ part, int H, int NCB, int Co, int Cop, int coOff) {
  __shared__ bf16_t Bb[2][4][4608];  // 72KB: double-buffered 4 input rows x 9 chunks
  const int tid = threadIdx.x;
  const int lane = tid & 63;
  const int wave = tid >> 6;
  const int wm = wave >> 1;  // co half (MF*16 channels)
  const int wp = wave & 1;   // px half (64 px)
  const int g = lane >> 4;   // k-group of 8
  const int ln = lane & 15;  // frag row/col
  constexpr int TILE = MF * 32;   // co per block (160 for MF=5)
  constexpr int EPS = TILE + 8;   // ep px stride (elems); 16B-aligned
  constexpr int NCO8 = TILE / 8;  // co-groups of 8 in store pass

  // XCD swizzle (nwg % 8 == 0 for all dispatches): contiguous chunk per XCD.
  const int gx = gridDim.x;
  const int nwg = gx * (int)gridDim.y;
  const int orig = (int)blockIdx.y * gx + (int)blockIdx.x;
  const int wg = (orig & 7) * (nwg >> 3) + (orig >> 3);
  const int coTile = coOff + (wg % gx) * TILE;
  const int bx = wg / gx;  // n*Hh + ypair
  const int Hh = H >> 1;
  const int n = bx / Hh, yp_ = bx % Hh;  // yp_ = pooled output row
  const int y0 = yp_ * 2;

  f32x4 acc0[MF][4], acc1[MF][4];
#pragma unroll
  for (int mf = 0; mf < MF; mf++)
#pragma unroll
    for (int nf = 0; nf < 4; nf++) {
      acc0[mf][nf] = (f32x4)(0.f);
      acc1[mf][nf] = (f32x4)(0.f);
    }

  const size_t cbStride = 4608;  // elems per (row, cb) slice
  const size_t rowStrideG = (size_t)NCB * cbStride;
  const size_t gRow0 = ((size_t)n * (H + 2) + y0) * rowStrideG;
  const size_t laneOff = (size_t)lane * 8;  // identity: lane L -> L*16B

  // A addressing: wt2 elem (((tap*NCB + cb)*4 + g)*Cop + co)*8,
  // co = coTile + wm*(MF*16) + mf*16 + ln.  mf -> imm offset (mf*256B).
  const size_t tapStrideA = (size_t)NCB * 4 * Cop * 8;  // elems per tap
  const size_t cbStrideA = (size_t)4 * Cop * 8;         // elems per cb
  const bf16_t* aLane = wt2 + ((size_t)g * Cop + coTile + wm * (MF * 16) + ln) * 8;

  // B fragment per-lane offsets: elem in row = wp*2048 + nf*512 + offdx[dx]
  int offdx[3];
#pragma unroll
  for (int dx = 0; dx < 3; ++dx) {
    int cx = ln + dx;
    offdx[dx] = wp * 2048 + ((cx & 15) * 8) + ((cx >> 4) * 512) + g * 128;
  }

  // prologue: stage cb=0 into buffer 0
  {
    const bf16_t* bsrc = xmT + gRow0;
    for (int c = wave; c < 36; c += 4) {
      int row = c / 9, chk = c - row * 9;
      __builtin_amdgcn_global_load_lds(
          (const __attribute__((address_space(1))) void*)(
              bsrc + (size_t)row * rowStrideG + chk * 512 + laneOff),
          (__attribute__((address_space(3))) void*)(&Bb[0][row][chk * 512]), 16, 0, 0);
    }
  }
  __syncthreads();

  int cur = 0;
  for (int cb = 0; cb < NCB; ++cb) {
    // prefetch next cb's B rows into the other buffer (hazard vs compute(cb-1)
    // reads of that buffer is covered by the bottom barrier of cb-1)
    if (cb + 1 < NCB) {
      const bf16_t* bsrc = xmT + gRow0 + (size_t)(cb + 1) * cbStride;
      for (int c = wave; c < 36; c += 4) {
        int row = c / 9, chk = c - row * 9;
        __builtin_amdgcn_global_load_lds(
            (const __attribute__((address_space(1))) void*)(
                bsrc + (size_t)row * rowStrideG + chk * 512 + laneOff),
            (__attribute__((address_space(3))) void*)(&Bb[cur ^ 1][row][chk * 512]), 16,
            0, 0);
      }
    }
    const bf16_t* aCb = aLane + (size_t)cb * cbStrideA;
#pragma unroll
    for (int dx = 0; dx < 3; ++dx) {
      bf16x8 a0[MF], a1[MF], a2[MF];
      bf16x8 b[4];
      // r=0: input row 0 -> o=0 only (dy=0, tap dx)
      {
        const bf16_t* aT = aCb + (size_t)dx * tapStrideA;
#pragma unroll
        for (int mf = 0; mf < MF; ++mf) a0[mf] = *(const bf16x8*)(aT + mf * 128);
        const bf16_t* bb = &Bb[cur][0][0] + offdx[dx];
#pragma unroll
        for (int nf = 0; nf < 4; ++nf) b[nf] = *(const bf16x8*)(bb + nf * 512);
#pragma unroll
        for (int nf = 0; nf < 4; ++nf)
#pragma unroll
          for (int mf = 0; mf < MF; ++mf)
            acc0[mf][nf] =
                __builtin_amdgcn_mfma_f32_16x16x32_bf16(a0[mf], b[nf], acc0[mf][nf], 0, 0, 0);
      }
      // r=1: row 1 -> o=0 (tap 3+dx) and o=1 (tap dx)
      {
        const bf16_t* aT = aCb + (size_t)(3 + dx) * tapStrideA;
#pragma unroll
        for (int mf = 0; mf < MF; ++mf) a1[mf] = *(const bf16x8*)(aT + mf * 128);
        const bf16_t* bb = &Bb[cur][1][0] + offdx[dx];
#pragma unroll
        for (int nf = 0; nf < 4; ++nf) b[nf] = *(const bf16x8*)(bb + nf * 512);
#pragma unroll
        for (int nf = 0; nf < 4; ++nf)
#pragma unroll
          for (int mf = 0; mf < MF; ++mf)
            acc0[mf][nf] =
                __builtin_amdgcn_mfma_f32_16x16x32_bf16(a1[mf], b[nf], acc0[mf][nf], 0, 0, 0);
#pragma unroll
        for (int nf = 0; nf < 4; ++nf)
#pragma unroll
          for (int mf = 0; mf < MF; ++mf)
            acc1[mf][nf] =
                __builtin_amdgcn_mfma_f32_16x16x32_bf16(a0[mf], b[nf], acc1[mf][nf], 0, 0, 0);
      }
      // r=2: row 2 -> o=0 (tap 6+dx) and o=1 (tap 3+dx)
      {
        const bf16_t* aT = aCb + (size_t)(6 + dx) * tapStrideA;
#pragma unroll
        for (int mf = 0; mf < MF; ++mf) a2[mf] = *(const bf16x8*)(aT + mf * 128);
        const bf16_t* bb = &Bb[cur][2][0] + offdx[dx];
#pragma unroll
        for (int nf = 0; nf < 4; ++nf) b[nf] = *(const bf16x8*)(bb + nf * 512);
#pragma unroll
        for (int nf = 0; nf < 4; ++nf)
#pragma unroll
          for (int mf = 0; mf < MF; ++mf)
            acc0[mf][nf] =
                __builtin_amdgcn_mfma_f32_16x16x32_bf16(a2[mf], b[nf], acc0[mf][nf], 0, 0, 0);
#pragma unroll
        for (int nf = 0; nf < 4; ++nf)
#pragma unroll
          for (int mf = 0; mf < MF; ++mf)
            acc1[mf][nf] =
                __builtin_amdgcn_mfma_f32_16x16x32_bf16(a1[mf], b[nf], acc1[mf][nf], 0, 0, 0);
      }
      // r=3: row 3 -> o=1 only (tap 6+dx)
      {
        const bf16_t* bb = &Bb[cur][3][0] + offdx[dx];
#pragma unroll
        for (int nf = 0; nf < 4; ++nf) b[nf] = *(const bf16x8*)(bb + nf * 512);
#pragma unroll
        for (int nf = 0; nf < 4; ++nf)
#pragma unroll
          for (int mf = 0; mf < MF; ++mf)
            acc1[mf][nf] =
                __builtin_amdgcn_mfma_f32_16x16x32_bf16(a2[mf], b[nf], acc1[mf][nf], 0, 0, 0);
      }
    }
    __syncthreads();  // compute(cb) reads done; prefetch(cb+1) drained
    cur ^= 1;
  }

  // ---- epilogue: scale+bias+mask, IN-REGISTER (2,1) POOL, fused BN stats ----
  const int pixBase0 = (n * H + y0) * WD;
  float scl0[4], msk0[4], scl1[4], msk1[4];
#pragma unroll
  for (int nf = 0; nf < 4; ++nf) {
    int x = wp * 64 + nf * 16 + ln;
    scl0[nf] = scale[pixBase0 + x];
    msk0[nf] = mnext[pixBase0 + x];
    scl1[nf] = scale[pixBase0 + WD + x];
    msk1[nf] = mnext[pixBase0 + WD + x];
  }
  float sA[4 * MF], qA[4 * MF];  // per-wave channel partials (64px x 2 rows)
#pragma unroll
  for (int i = 0; i < 4 * MF; ++i) { sA[i] = 0.f; qA[i] = 0.f; }
  bf16_t* ep = &Bb[0][0][0];  // 128px x EPS elems x 2B = 43008B <= 73728B
#pragma unroll
  for (int mf = 0; mf < MF; ++mf) {
    int cbase = wm * (MF * 16) + mf * 16;
    f32x4 bias4 = *(const f32x4*)&bias[coTile + cbase + g * 4];
#pragma unroll
    for (int nf = 0; nf < 4; ++nf) {
      bf16x4 o;
#pragma unroll
      for (int r = 0; r < 4; ++r) {
        bf16_t v0 = (bf16_t)((acc0[mf][nf][r] * scl0[nf] + bias4[r]) * msk0[nf]);
        bf16_t v1 = (bf16_t)((acc1[mf][nf][r] * scl1[nf] + bias4[r]) * msk1[nf]);
        float f0 = (float)v0, f1 = (float)v1;  // stats from rounded values
        sA[mf * 4 + r] += f0 + f1;
        qA[mf * 4 + r] += f0 * f0 + f1 * f1;
        o[r] = (bf16_t)fmaxf(f0, f1);
      }
      *(bf16x4*)&ep[(wp * 64 + nf * 16 + ln) * EPS + cbase + g * 4] = o;
    }
  }
  __syncthreads();
  // pooled store: one row per block at half height
  {
    const size_t prow = ((size_t)n * Hh + yp_) * WD;
    for (int idx = tid; idx < 128 * NCO8; idx += 256) {
      int cgrp = idx % NCO8;
      int p = idx / NCO8;
      bf16x8 v = *(const bf16x8*)&ep[p * EPS + cgrp * 8];
      *(bf16x8*)&y[(prow + p) * Co + coTile + cgrp * 8] = v;
    }
  }

  // ---- fused BN stats: DPP rowsum over the 16-lane px group, then PLAIN
  // STORES of per-(block,wave) partials -- no atomics (r20's lesson).
#pragma unroll
  for (int i = 0; i < 4 * MF; ++i) {
    sA[i] = rowsum16(sA[i]);
    qA[i] = rowsum16(qA[i]);
  }
  if (ln == 15) {  // full group sum lives in the HIGHEST lane of each 16-group
    const int row = bx * 2 + wp;  // unique per (block, wp); co spans wm
#pragma unroll
    for (int i = 0; i < 4 * MF; ++i) {
      int co = coTile + wm * (MF * 16) + (i >> 2) * 16 + g * 4 + (i & 3);
      part[(size_t)co * PROWS + row] = sA[i];
      part[(size_t)PCO * PROWS + (size_t)co * PROWS + row] = qA[i];
    }
  }
}

// ---------------- BN partial reduce + finalize (all stages) ----------------
__global__ __launch_bounds__(256) void bnfin_r(const float* __restrict__ part,
                                               const float* __restrict__ g,
                                               const float* __restrict__ be,
                                               float* __restrict__ ab, int Co,
                                               int rows, int stride,
                                               float invCount) {
  int c = blockIdx.x;
  int tid = threadIdx.x;
  float s = 0.f, q = 0.f;
  for (int r = tid; r < rows; r += 256) {
    s += part[(size_t)c * stride + r];
    q += part[(size_t)PCO * PROWS + (size_t)c * stride + r];
  }
  __shared__ float rs[256], rq[256];
  rs[tid] = s;
  rq[tid] = q;
  __syncthreads();
  for (int off = 128; off > 0; off >>= 1) {
    if (tid < off) {
      rs[tid] += rs[tid + off];
      rq[tid] += rq[tid + off];
    }
    __syncthreads();
  }
  if (tid == 0) {
    float mean = rs[0] * invCount;
    float var = rq[0] * invCount - mean * mean;
    float rsq = rsqrtf(var + 1e-5f);
    float a = g[c] * rsq;
    ab[c] = a;
    ab[Co + c] = be[c] - mean * a;
  }
}

// ---------------- BN + ReLU + mask on POOLED input -> chunked padded xmT ----------------
__global__ void bnpoolp_k(const bf16_t* __restrict__ yp, const float* __restrict__ ab,
                          const float* __restrict__ mp, bf16_t* __restrict__ out, int C,
                          int NCBn, int Hp) {
  int Cq = C / 8;
  int tid = blockIdx.x * 256 + threadIdx.x;
  int total = NB * Hp * WD * Cq;
  if (tid >= total) return;
  int c8 = tid % Cq;
  int t = tid / Cq;
  int x = t % WD;
  t /= WD;
  int yo = t % Hp;
  int n = t / Hp;
  int c = c8 * 8;
  const bf16_t* p0 = yp + ((size_t)((n * Hp + yo) * WD + x)) * C + c;
  float mpv = mp[(n * Hp + yo) * WD + x];
  bf16x8 v0 = *(const bf16x8*)p0;
  bf16x8 o;
#pragma unroll
  for (int j = 0; j < 8; ++j) {
    float a = ab[c + j], sh = ab[C + c + j];
    float f0 = (float)v0[j] * a + sh;
    o[j] = (bf16_t)(fmaxf(f0, 0.f) * mpv);
  }
  int cb = c >> 5;
  int gg = (c & 31) >> 3;
  int col = x + 1;
  int chk = col >> 4, lcol = col & 15;
  *(bf16x8*)&out[((((size_t)n * (Hp + 2) + yo + 1) * NCBn + cb) * 9 + chk) * 512 +
                 gg * 128 + lcol * 8] = o;
}

// ---------------- stage-4: BN + ReLU + global mean on POOLED input -> feat ----------------
__global__ void bnfeatp_k(const bf16_t* __restrict__ yp, const float* __restrict__ ab,
                          float* __restrict__ feat) {
  int n = blockIdx.x, cc = blockIdx.y, yo = blockIdx.z;  // yo < 16 pooled rows
  int c = cc * 128 + threadIdx.x;  // C = 640
  float a = ab[c], sh = ab[640 + c];
  float s = 0.f;
  for (int x = 0; x < WD; ++x) {
    size_t p0 = ((size_t)(n * 16 + yo) * WD + x) * 640 + c;
    float v = (float)yp[p0] * a + sh;
    s += fmaxf(v, 0.f);
  }
  atomicAdd(&feat[n * 640 + c], s * (1.f / 2048.f));
}

// ---------------- fc1 (640->256) + relu ----------------
__global__ void fc1_k(const float* __restrict__ feat, const float* __restrict__ fw,
                      const float* __restrict__ fb, float* __restrict__ z1) {
  int n = blockIdx.x;
  int o = threadIdx.x;
  const float* f = feat + n * 640;
  const float* wr = fw + o * 640;
  float s = fb[o];
  for (int k = 0; k < 640; k++) s += f[k] * wr[k];
  z1[n * 256 + o] = fmaxf(s, 0.f);
}

// ---------------- fc2 (256->128) + relu + head + sigmoid ----------------
__global__ void fc2h_k(const float* __restrict__ z1, const float* __restrict__ fw2,
                       const float* __restrict__ fb2, const float* __restrict__ hw,
                       const float* __restrict__ hb, float* __restrict__ out) {
  int n = blockIdx.x;
  int o = threadIdx.x;
  const float* zr = z1 + n * 256;
  const float* wr = fw2 + o * 256;
  float s = fb2[o];
  for (int k = 0; k < 256; k++) s += zr[k] * wr[k];
  s = fmaxf(s, 0.f) * hw[o];
#pragma unroll
  for (int off = 32; off >= 1; off >>= 1) s += __shfl_down(s, off, 64);
  __shared__ float red[2];
  if ((threadIdx.x & 63) == 0) red[threadIdx.x >> 6] = s;
  __syncthreads();
  if (threadIdx.x == 0) {
    float t = red[0] + red[1] + hb[0];
    out[n] = 1.f / (1.f + expf(-t));
  }
}

extern "C" void kernel_launch(void* const* d_in, const int* in_sizes, int n_in,
                              void* d_out, int out_size, void* d_ws, size_t ws_size,
                              hipStream_t stream) {
  const float* x = (const float*)d_in[0];
  const float* wgt[4] = {(const float*)d_in[1], (const float*)d_in[5],
                         (const float*)d_in[9], (const float*)d_in[13]};
  const float* bias[4] = {(const float*)d_in[2], (const float*)d_in[6],
                          (const float*)d_in[10], (const float*)d_in[14]};
  const float* gam[4] = {(const float*)d_in[3], (const float*)d_in[7],
                         (const float*)d_in[11], (const float*)d_in[15]};
  const float* bet[4] = {(const float*)d_in[4], (const float*)d_in[8],
                         (const float*)d_in[12], (const float*)d_in[16]};
  const float* fw1 = (const float*)d_in[17];
  const float* fb1 = (const float*)d_in[18];
  const float* fw2 = (const float*)d_in[19];
  const float* fb2 = (const float*)d_in[20];
  const float* hw = (const float*)d_in[21];
  const float* hb = (const float*)d_in[22];

  char* base = (char*)d_ws;
  size_t off = 0;
  auto alloc = [&](size_t bytes) {
    char* p = base + off;
    off += (bytes + 255) & ~(size_t)255;
    return p;
  };
  bf16_t* bufY = (bf16_t*)alloc(83886080);  // 41,943,040 bf16
  const size_t xmtElems = 28786688;         // 16*130*3*4608 + 32768 slack
  bf16_t* xmT0 = (bf16_t*)alloc(xmtElems * 2);
  bf16_t* xmT1 = (bf16_t*)alloc(xmtElems * 2);
  bf16_t* wt2 = (bf16_t*)alloc(3686400);
  float* mask0 = (float*)alloc(2097152);
  float* mask1 = (float*)alloc(2097152);
  float* scaleB = (float*)alloc(2097152);
  float* mnextB = (float*)alloc(2097152);
  float* part = (float*)alloc((size_t)2 * 640 * 2048 * 4);  // 10.5MB BN partials
  float* bnab = (float*)alloc(5120);
  float* feat = (float*)alloc(40960);
  float* z1 = (float*)alloc(16384);

  zero_k<<<40, 256, 0, stream>>>(feat, 10240);

  // ---------- stage 1 (direct from x, Ci=1, Co=80; fused scale+pool+stats) ----------
  {
    int H = 256;
    int totp2 = NB * (H / 2) * WD;  // pooled pixels
    ms1_k<<<(totp2 + 255) / 256, 256, 0, stream>>>(x, mask1);
    pconv1p_k<<<totp2 / 256, 256, 0, stream>>>(x, wgt[0], bias[0], bufY, part);
    bnfin_r<<<80, 256, 0, stream>>>(part, gam[0], bet[0], bnab, 80, P1STR, P1STR,
                                    1.0f / (NB * (float)H * WD));
    {
      int tz = NB * 2 * 3 * 576 + NB * 128 * 3 * 8;
      zb_k<<<(tz + 255) / 256, 256, 0, stream>>>(xmT0, 128, 3);
    }
    int totp = NB * 128 * WD * (80 / 8);
    bnpoolp_k<<<(totp + 255) / 256, 256, 0, stream>>>(bufY, bnab, mask1, xmT0, 80, 3,
                                                      128);
  }

  // ---------- stages 2-4 (MFMA implicit GEMM, fused pool, 160-co tiles) ----------
  const int CiS[3] = {80, 160, 320};
  const int NCBS[3] = {3, 5, 10};
  const int CoS[3] = {160, 320, 640};
  const int HS[3] = {128, 64, 32};
  bf16_t* xin[3] = {xmT0, xmT1, xmT0};
  bf16_t* xout[3] = {xmT1, xmT0, nullptr};
  float* mIn[3] = {mask1, mask0, mask1};
  float* mOut[3] = {mask0, mask1, mask0 /* scratch for s==2 */};

  for (int s = 0; s < 3; ++s) {
    int H = HS[s], Ci = CiS[s], NCB = NCBS[s], Co = CoS[s];
    // wt2 unpadded: Cop = Co
    int wtot = 9 * NCB * Co * 32;
    wtrans_k<<<(wtot + 255) / 256, 256, 0, stream>>>(wgt[s + 1], wt2, Ci, Co, NCB, Co);
    int tot = NB * H * WD;
    maskscale2_k<<<(tot / 2 + 255) / 256, 256, 0, stream>>>(mIn[s], scaleB, mnextB,
                                                            mOut[s], H, (float)Ci);
    int Hh2 = NB * (H / 2);  // 1024 / 512 / 256 y-pairs
    int tiles = Co / 160;    // 1 / 2 / 4 tiles of 160 co -- exact for all stages
    convmfma_t<5><<<dim3(tiles, Hh2), 256, 0, stream>>>(
        xin[s], wt2, bias[s + 1], scaleB, mnextB, bufY, part, H, NCB, Co, Co, 0);
    bnfin_r<<<Co, 256, 0, stream>>>(part, gam[s + 1], bet[s + 1], bnab, Co, NB * H,
                                    PROWS, 1.0f / (NB * (float)H * WD));
    if (s < 2) {
      int Hpn = H / 2, NCBn = NCBS[s + 1];
      int tz = NB * 2 * NCBn * 576 + NB * Hpn * NCBn * 8;
      zb_k<<<(tz + 255) / 256, 256, 0, stream>>>(xout[s], Hpn, NCBn);
      int totp = NB * Hpn * WD * (Co / 8);
      bnpoolp_k<<<(totp + 255) / 256, 256, 0, stream>>>(bufY, bnab, mOut[s], xout[s],
                                                        Co, NCBn, Hpn);
    } else {
      bnfeatp_k<<<dim3(16, 5, 16), 128, 0, stream>>>(bufY, bnab, feat);
    }
  }

  fc1_k<<<16, 256, 0, stream>>>(feat, fw1, fb1, z1);
  fc2h_k<<<16, 128, 0, stream>>>(z1, fw2, fb2, hw, hb, (float*)d_out);
}